// Round 4
// baseline (253.344 us; speedup 1.0000x reference)
//
#include <hip/hip_runtime.h>

// Cost-volume / correlation layer, fp32.
// out[b, dy*9+dx, h, w] = (1/C) * sum_c first[b,c,h,w] * second[b,c,h+dy-4,w+dx-4]
// (zero outside bounds).  B=8, C=128, H=W=128, search_range=4 -> 81 offsets.
//
// Round-4: R2/R3 were bound by serialized long-latency loads (VGPR=44 proved
// loads were consumed one-by-one; L3 serves the 9x dy re-read at ~500+ cyc).
// Changes:
//  (1) explicit 2-bank, distance-2 pipeline with sched_barrier(0) fences so
//      each 4-load batch stays in flight across a compute block;
//  (2) XCD-aware swizzle: 1152 blocks = 8 XCD x 16 (b,htile) pairs x 9 dy,
//      all co-resident; give each XCD all 9 dy of its 16 pairs so dy re-reads
//      hit that XCD's L2 instead of L3.

constexpr int B = 8, C = 128, H = 128, W = 128;
constexpr int RNG = 4, MO = 9;   // search range, max_offset = 2*RNG+1
constexpr int RW  = 4;           // pixels per thread along w
constexpr int TY  = 8;           // pixel rows per block

__global__ __launch_bounds__(256) void corr_kernel(
    const float* __restrict__ first,
    const float* __restrict__ second,
    float* __restrict__ out)
{
    // ---- XCD-aware block decode: lin = 8*(pr*9+dy) + xcd ; pair = xcd*16+pr
    const int lin   = blockIdx.x;          // 0..1151
    const int xcd   = lin & 7;
    const int slot  = lin >> 3;            // 0..143
    const int dy    = slot % MO;           // 0..8
    const int pr    = slot / MO;           // 0..15
    const int pair  = xcd * 16 + pr;       // 0..127
    const int b     = pair >> 4;           // 0..7
    const int htile = pair & 15;           // 0..15

    const int tx = threadIdx.x;            // 0..31
    const int ty = threadIdx.y;            // 0..7
    const int h  = htile * TY + ty;        // 0..127
    const int w0 = tx * RW;                // 0..124

    float acc[MO][RW];
#pragma unroll
    for (int dx = 0; dx < MO; ++dx)
#pragma unroll
        for (int p = 0; p < RW; ++p) acc[dx][p] = 0.0f;

    const size_t HW = (size_t)H * W;
    const float* fptr = first + (size_t)b * C * HW + (size_t)h * W + w0;

    const int  srow_i = h + dy - RNG;
    const bool rvalid = (srow_i >= 0) && (srow_i < H);
    const int  srow_c = srow_i < 0 ? 0 : (srow_i >= H ? H - 1 : srow_i);
    const float* sptr = second + (size_t)b * C * HW + (size_t)srow_c * W;

    // Column edges: tx==0 needs cols -4..-1 (zero), tx==31 needs 128..131.
    const bool ledge = (tx == 0);
    const bool redge = (tx == 31);
    const int off0 = ledge ? 0       : (w0 - 4);   // 16B-aligned
    const int off2 = redge ? (W - 8) : (w0 + 4);

    if (rvalid) {
        const size_t HW2 = 2 * HW, HW3 = 3 * HW;
        const float* pf = fptr;
        const float* ps = sptr;

        float4 fA, a0A, a1A, a2A, fB, a0B, a1B, a2B;

#define LOADA(OFS)                                                          \
        {                                                                   \
            fA  = *(const float4*)(pf + (OFS));                             \
            a0A = *(const float4*)(ps + (OFS) + off0);                      \
            a1A = *(const float4*)(ps + (OFS) + w0);                       \
            a2A = *(const float4*)(ps + (OFS) + off2);                      \
        }
#define LOADB(OFS)                                                          \
        {                                                                   \
            fB  = *(const float4*)(pf + (OFS));                             \
            a0B = *(const float4*)(ps + (OFS) + off0);                      \
            a1B = *(const float4*)(ps + (OFS) + w0);                       \
            a2B = *(const float4*)(ps + (OFS) + off2);                      \
        }
#define COMPUTE(SET)                                                        \
        {                                                                   \
            float4 z0 = a0##SET, z2 = a2##SET;                              \
            if (ledge) z0 = make_float4(0.f, 0.f, 0.f, 0.f);                \
            if (redge) z2 = make_float4(0.f, 0.f, 0.f, 0.f);                \
            float fv[RW] = {f##SET.x, f##SET.y, f##SET.z, f##SET.w};        \
            float s[12]  = {z0.x, z0.y, z0.z, z0.w,                         \
                            a1##SET.x, a1##SET.y, a1##SET.z, a1##SET.w,     \
                            z2.x, z2.y, z2.z, z2.w};                        \
            _Pragma("unroll")                                               \
            for (int dx = 0; dx < MO; ++dx)                                 \
                _Pragma("unroll")                                           \
                for (int p = 0; p < RW; ++p)                                \
                    acc[dx][p] += fv[p] * s[p + dx];                        \
        }

        // prologue: c=0 -> bank A, c=1 -> bank B
        LOADA(0)
        LOADB(HW)
        __builtin_amdgcn_sched_barrier(0);

        // steady state: compute c,c+1 while c+2,c+3 are in flight
        for (int c = 0; c < C - 2; c += 2) {
            COMPUTE(A)                       // waits vmcnt for A only
            __builtin_amdgcn_sched_barrier(0);
            LOADA(HW2)                       // refill A with c+2
            __builtin_amdgcn_sched_barrier(0);
            COMPUTE(B)                       // waits vmcnt for B only
            __builtin_amdgcn_sched_barrier(0);
            LOADB(HW3)                       // refill B with c+3
            __builtin_amdgcn_sched_barrier(0);
            pf += HW2;
            ps += HW2;
        }
        // epilogue: c = 126, 127
        COMPUTE(A)
        COMPUTE(B)

#undef LOADA
#undef LOADB
#undef COMPUTE
    }

    const float inv = 1.0f / (float)C;
    float* obase = out + ((size_t)b * (MO * MO) + (size_t)dy * MO) * HW
                       + (size_t)h * W + w0;
#pragma unroll
    for (int dx = 0; dx < MO; ++dx) {
        float4 v = make_float4(acc[dx][0] * inv, acc[dx][1] * inv,
                               acc[dx][2] * inv, acc[dx][3] * inv);
        *(float4*)(obase + (size_t)dx * HW) = v;
    }
}

extern "C" void kernel_launch(void* const* d_in, const int* in_sizes, int n_in,
                              void* d_out, int out_size, void* d_ws, size_t ws_size,
                              hipStream_t stream) {
    const float* first  = (const float*)d_in[0];
    const float* second = (const float*)d_in[1];
    float* out = (float*)d_out;

    dim3 grid(16 * MO * B);     // 1152 blocks, 1-D for XCD swizzle decode
    dim3 block(32, TY);         // 256 threads
    corr_kernel<<<grid, block, 0, stream>>>(first, second, out);
}

// Round 5
// 238.895 us; speedup vs baseline: 1.0605x; 1.0605x over previous
//
#include <hip/hip_runtime.h>

// Cost-volume / correlation layer, fp32.
// out[b, dy*9+dx, h, w] = (1/C) * sum_c first[b,c,h,w] * second[b,c,h+dy-4,w+dx-4]
// (zero outside bounds).  B=8, C=128, H=W=128, search_range=4 -> 81 offsets.
//
// Round-5: R2/R3 pinned at 127us by L1 delivered bytes (64 B/lane/c; the 3
// second-loads re-read the same lines 3x through L1). Fix: stage the second
// row-tile in LDS (each thread ds_writes ONE float4/c; halo re-reads move to
// the idle LDS pipe), zero-padded +/-4-col halo kills edge cndmasks,
// double-buffered with 1 barrier/c, distance-1 register prefetch of staging
// loads.  Keep R4's XCD swizzle (FETCH 97->69 MB), drop sched_barrier fences
// (they caused R4's regression, m141-style).

constexpr int B = 8, C = 128, H = 128, W = 128;
constexpr int RNG = 4, MO = 9;   // search range, max_offset = 2*RNG+1
constexpr int RW  = 4;           // pixels per thread along w
constexpr int TY  = 8;           // pixel rows per block
constexpr int LROW = 144;        // LDS row: 4 zero + 128 data + 4 zero + 8 pad

__global__ __launch_bounds__(256) void corr_kernel(
    const float* __restrict__ first,
    const float* __restrict__ second,
    float* __restrict__ out)
{
    // XCD-aware decode: all 9 dy of a (b,htile) pair land on one XCD's L2.
    const int lin   = blockIdx.x;          // 0..1151
    const int xcd   = lin & 7;
    const int slot  = lin >> 3;            // 0..143
    const int dy    = slot % MO;
    const int pr    = slot / MO;           // 0..15
    const int pair  = xcd * 16 + pr;       // 0..127
    const int b     = pair >> 4;
    const int htile = pair & 15;

    const int tx = threadIdx.x;            // 0..31
    const int ty = threadIdx.y;            // 0..7
    const int h0 = htile * TY;
    const int h  = h0 + ty;
    const int w0 = tx * RW;                // 0..124

    __shared__ float sbuf[2][TY][LROW];    // 9216 B

    // Zero the column halo once (padded cols 0..3 and 132..135), both buffers.
    if (tx < 2) {
        const int p = (tx == 0) ? 0 : 132;
        *(float4*)&sbuf[0][ty][p] = make_float4(0.f, 0.f, 0.f, 0.f);
        *(float4*)&sbuf[1][ty][p] = make_float4(0.f, 0.f, 0.f, 0.f);
    }

    float acc[MO][RW];
#pragma unroll
    for (int dx = 0; dx < MO; ++dx)
#pragma unroll
        for (int p = 0; p < RW; ++p) acc[dx][p] = 0.0f;

    const size_t HW = (size_t)H * W;
    const float* fptr = first + (size_t)b * C * HW + (size_t)h * W + w0;

    // Staging duty: thread-row ty stages s-row r = h0 + ty + dy - 4
    // (the exact row thread-row ty's pixels need). Out-of-range rows -> zeros.
    const int  sr  = h0 + ty + dy - RNG;
    const bool srv = (sr >= 0) && (sr < H);
    const float* sptr = second + (size_t)b * C * HW
                               + (size_t)(srv ? sr : 0) * W + w0;

    const float4 zero4 = make_float4(0.f, 0.f, 0.f, 0.f);

    // ---- prologue: c = 0 ----
    float4 fv = *(const float4*)(fptr);
    float4 sv = srv ? *(const float4*)(sptr) : zero4;
    *(float4*)&sbuf[0][ty][4 + w0] = sv;
    __syncthreads();

    int cur = 0;
    for (int c = 0; c < C; ++c) {
        // prefetch c+1 (clamped; last-iter values are discarded)
        const size_t onx = (size_t)(c + 1 < C ? c + 1 : c) * HW;
        float4 fN = *(const float4*)(fptr + onx);
        float4 sN = srv ? *(const float4*)(sptr + onx) : zero4;

        // compute from sbuf[cur]: padded col 4tx = image col w0-4
        float4 a0 = *(const float4*)&sbuf[cur][ty][w0];
        float4 a1 = *(const float4*)&sbuf[cur][ty][w0 + 4];
        float4 a2 = *(const float4*)&sbuf[cur][ty][w0 + 8];
        float fvv[RW] = {fv.x, fv.y, fv.z, fv.w};
        float s[12]   = {a0.x, a0.y, a0.z, a0.w,
                         a1.x, a1.y, a1.z, a1.w,
                         a2.x, a2.y, a2.z, a2.w};
#pragma unroll
        for (int dx = 0; dx < MO; ++dx)
#pragma unroll
            for (int p = 0; p < RW; ++p)
                acc[dx][p] += fvv[p] * s[p + dx];

        // stage c+1 into the other buffer
        *(float4*)&sbuf[cur ^ 1][ty][4 + w0] = sN;
        __syncthreads();
        fv  = fN;
        cur ^= 1;
    }

    const float inv = 1.0f / (float)C;
    float* obase = out + ((size_t)b * (MO * MO) + (size_t)dy * MO) * HW
                       + (size_t)h * W + w0;
#pragma unroll
    for (int dx = 0; dx < MO; ++dx) {
        float4 v = make_float4(acc[dx][0] * inv, acc[dx][1] * inv,
                               acc[dx][2] * inv, acc[dx][3] * inv);
        *(float4*)(obase + (size_t)dx * HW) = v;
    }
}

extern "C" void kernel_launch(void* const* d_in, const int* in_sizes, int n_in,
                              void* d_out, int out_size, void* d_ws, size_t ws_size,
                              hipStream_t stream) {
    const float* first  = (const float*)d_in[0];
    const float* second = (const float*)d_in[1];
    float* out = (float*)d_out;

    dim3 grid(16 * MO * B);     // 1152 blocks, 1-D for XCD swizzle decode
    dim3 block(32, TY);         // 256 threads
    corr_kernel<<<grid, block, 0, stream>>>(first, second, out);
}